// Round 12
// baseline (173.160 us; speedup 1.0000x reference)
//
#include <hip/hip_runtime.h>

// out[b,o,n] = max_d |x[b,d,n] - w[o,d]| + bias[o]
// B=64, CIN=1024, COUT=1024, N=49. Pixels P = B*N = 3136.
//
// Round-12: x transposed once to xT[k][p] (prologue kernel, d_ws) so each
// lane's pixel-PAIR at one k is a single dwordx2 -> 4 x-load instrs per
// 4-k stage (was 8 scalar + heavy addressing; x-path was ~25% of issue).
// pk pairing now (px0,px1) with w broadcast via VOP3P op_sel (no movs):
//   d0 = v_pk_add_f32(wpair.lo bcast, xpair)  [k even]
//   d1 = v_pk_add_f32(wpair.hi bcast, xpair)  [k odd]
//   acc[c][px] = v_max3(acc, |d_even.px|, |d_odd.px|)
// w: r11-proven opaque asm s_load_dwordx4 pipeline (issue t+1, compute t,
// drain, + sched_barrier(0) per rule #18 to stop VALU hoisting past the wait).
// CPW=8 (x L2 traffic ~1.6GB), grid (128 cg, 25 pt) = 3200 blocks, cgroup-fast
// dispatch -> the 128 blocks sharing a pixel tile are co-resident (L2 hits).

typedef float v2f  __attribute__((ext_vector_type(2)));
typedef float v4sf __attribute__((ext_vector_type(4)));

constexpr int CIN  = 1024;
constexpr int COUT = 1024;
constexpr int NN   = 49;
constexpr int P    = 3136;
constexpr int CPW  = 8;                 // channels per wave
constexpr int PT   = 128;               // pixels per tile (2 per lane)
constexpr int NPT  = 25;                // 24 full + 1 ragged (64 px)
constexpr int NTL  = CIN / 4;           // 256 k-stages

// packed sub with w broadcast: lo-half of wpair to both halves / hi-half to both
#define PKBC_LO(d, wp, xp) \
    asm("v_pk_add_f32 %0, %1, %2 op_sel:[0,0] op_sel_hi:[0,1] neg_lo:[1,0] neg_hi:[1,0]" \
        : "=v"(d) : "s"(wp), "v"(xp))
#define PKBC_HI(d, wp, xp) \
    asm("v_pk_add_f32 %0, %1, %2 op_sel:[1,0] op_sel_hi:[1,1] neg_lo:[1,0] neg_hi:[1,0]" \
        : "=v"(d) : "s"(wp), "v"(xp))
#define AMAX3(a, lo, hi) \
    asm("v_max3_f32 %0, %0, |%1|, |%2|" : "+v"(a) : "v"(lo), "v"(hi))
// pair-sub for the fallback kernel (k-pair in both operands)
#define PKSUB(d, wp, xp) \
    asm("v_pk_add_f32 %0, %1, %2 neg_lo:[0,1] neg_hi:[0,1]" \
        : "=v"(d) : "s"(wp), "v"(xp))

// 8 channels x 4 k: immediate offsets c*CIN*4B = c*0x1000 off one base.
#define ISSUE_W(buf, ptr) do {                                               \
    asm volatile("s_load_dwordx4 %0, %1, 0x0"    : "=s"(buf[0]) : "s"(ptr)); \
    asm volatile("s_load_dwordx4 %0, %1, 0x1000" : "=s"(buf[1]) : "s"(ptr)); \
    asm volatile("s_load_dwordx4 %0, %1, 0x2000" : "=s"(buf[2]) : "s"(ptr)); \
    asm volatile("s_load_dwordx4 %0, %1, 0x3000" : "=s"(buf[3]) : "s"(ptr)); \
    asm volatile("s_load_dwordx4 %0, %1, 0x4000" : "=s"(buf[4]) : "s"(ptr)); \
    asm volatile("s_load_dwordx4 %0, %1, 0x5000" : "=s"(buf[5]) : "s"(ptr)); \
    asm volatile("s_load_dwordx4 %0, %1, 0x6000" : "=s"(buf[6]) : "s"(ptr)); \
    asm volatile("s_load_dwordx4 %0, %1, 0x7000" : "=s"(buf[7]) : "s"(ptr)); \
} while (0)
#define SDRAIN() do { asm volatile("s_waitcnt lgkmcnt(0)" ::: "memory"); \
                      __builtin_amdgcn_sched_barrier(0); } while (0)

// xT[k][p] = x[b][k][n], p = b*49+n. grid (49, 256), block 256 (64 p x 4 k).
__global__ void transpose_x(const float* __restrict__ x, float* __restrict__ xT) {
    const int pp = threadIdx.x & 63, kk = threadIdx.x >> 6;
    const int p = blockIdx.x * 64 + pp;
    const int k = blockIdx.y * 4 + kk;
    const int b = p / NN, n = p - b * NN;
    xT[(size_t)k * P + p] = x[(size_t)b * (CIN * NN) + (size_t)k * NN + n];
}

__global__ __launch_bounds__(64) void ndist_kernel(
    const float* __restrict__ xT, const float* __restrict__ w,
    const float* __restrict__ bias, float* __restrict__ out)
{
    const int lane  = threadIdx.x;            // 0..63
    const int o0    = blockIdx.x * CPW;
    const int pbase = blockIdx.y * PT;
    const int p0    = pbase + 2 * lane;                 // this lane's pixel pair
    const int pc    = (p0 <= P - 2) ? p0 : (P - 2);     // clamped (even, 8B-aligned)

    const float* __restrict__ xb = xT + pc;             // + k*P per row
    const float* wb = w + (size_t)o0 * CIN;             // uniform base (asm s_load)

    float acc[CPW][2];
#pragma unroll
    for (int c = 0; c < CPW; ++c) { acc[c][0] = 0.0f; acc[c][1] = 0.0f; }

    v2f  xA[4], xB[4];      // x pixel-pairs for 4 k's, double-buffered
    v4sf wS0[8], wS1[8];    // w k-quads per channel, ping-pong (asm-managed)

#define LOAD_X(dst, kt) do {                                   \
        _Pragma("unroll")                                      \
        for (int j = 0; j < 4; ++j)                            \
            dst[j] = *(const v2f*)(xb + (size_t)((kt) * 4 + j) * P); \
    } while (0)

    // per channel: 4 pk + 4 max3 covering 4 k x 2 px = 8 updates
#define COMPUTE(xv, wbuf) do {                                 \
        _Pragma("unroll")                                      \
        for (int c = 0; c < CPW; ++c) {                        \
            v2f p01 = __builtin_shufflevector(wbuf[c], wbuf[c], 0, 1); \
            v2f p23 = __builtin_shufflevector(wbuf[c], wbuf[c], 2, 3); \
            v2f d0, d1, d2, d3;                                \
            PKBC_LO(d0, p01, xv[0]);                           \
            PKBC_HI(d1, p01, xv[1]);                           \
            AMAX3(acc[c][0], d0.x, d1.x);                      \
            AMAX3(acc[c][1], d0.y, d1.y);                      \
            PKBC_LO(d2, p23, xv[2]);                           \
            PKBC_HI(d3, p23, xv[3]);                           \
            AMAX3(acc[c][0], d2.x, d3.x);                      \
            AMAX3(acc[c][1], d2.y, d3.y);                      \
        }                                                      \
    } while (0)

    // prologue
    ISSUE_W(wS0, wb);
    LOAD_X(xA, 0);
    SDRAIN();

    // main: [issue W(t+1), X(t+1)] [compute t] [drain+fence] ...
    for (int kt = 0; kt < NTL - 2; kt += 2) {
        ISSUE_W(wS1, wb + (size_t)(kt + 1) * 4);
        LOAD_X(xB, kt + 1);
        COMPUTE(xA, wS0);
        SDRAIN();

        ISSUE_W(wS0, wb + (size_t)(kt + 2) * 4);
        LOAD_X(xA, kt + 2);
        COMPUTE(xB, wS1);
        SDRAIN();
    }
    {   // stages 254, 255 (no over-issue)
        ISSUE_W(wS1, wb + (size_t)(NTL - 1) * 4);
        LOAD_X(xB, NTL - 1);
        COMPUTE(xA, wS0);
        SDRAIN();
        COMPUTE(xB, wS1);
    }

    // epilogue: per-pixel guard (divergent only in the ragged 25th tile)
#pragma unroll
    for (int c = 0; c < CPW; ++c) {
        const int o = o0 + c;
        const float bv = bias[o];
#pragma unroll
        for (int i = 0; i < 2; ++i) {
            const int px = p0 + i;
            if (px < P) {
                const int b = px / NN, n = px - b * NN;
                out[((size_t)b * COUT + o) * NN + n] = acc[c][i] + bv;
            }
        }
    }
}

// ---- fallback (round-6 structure, known-correct) if ws too small ----
__global__ __launch_bounds__(128) void ndist_fallback(
    const float* __restrict__ x, const float* __restrict__ w,
    const float* __restrict__ bias, float* __restrict__ out)
{
    const int lane = threadIdx.x & 63;
    const int wid  = __builtin_amdgcn_readfirstlane(threadIdx.x >> 6);
    const int p = blockIdx.y * 64 + lane;
    const int b = p / NN, n = p - b * NN;
    const int o0 = blockIdx.x * 16 + wid * 8;
    const float* __restrict__ xrow = x + (size_t)b * CIN * NN + n;
    const float* __restrict__ wb   = w + (size_t)o0 * CIN;

    float acc[8];
#pragma unroll
    for (int c = 0; c < 8; ++c) acc[c] = 0.0f;

    for (int kt = 0; kt < NTL; ++kt) {
        v2f xv0 = { xrow[(kt * 4 + 0) * NN], xrow[(kt * 4 + 1) * NN] };
        v2f xv1 = { xrow[(kt * 4 + 2) * NN], xrow[(kt * 4 + 3) * NN] };
#pragma unroll
        for (int c = 0; c < 8; ++c) {
            v4sf t = *(const v4sf*)(wb + (size_t)c * CIN + kt * 4);
            v2f lo = __builtin_shufflevector(t, t, 0, 1);
            v2f hi = __builtin_shufflevector(t, t, 2, 3);
            v2f d0, d1;
            PKSUB(d0, lo, xv0);
            PKSUB(d1, hi, xv1);
            AMAX3(acc[c], d0.x, d0.y);
            AMAX3(acc[c], d1.x, d1.y);
        }
    }
#pragma unroll
    for (int c = 0; c < 8; ++c) {
        const int o = o0 + c;
        out[((size_t)b * COUT + o) * NN + n] = acc[c] + bias[o];
    }
}

extern "C" void kernel_launch(void* const* d_in, const int* in_sizes, int n_in,
                              void* d_out, int out_size, void* d_ws, size_t ws_size,
                              hipStream_t stream) {
    const float* x    = (const float*)d_in[0];
    const float* w    = (const float*)d_in[1];
    const float* bias = (const float*)d_in[2];
    float* out        = (float*)d_out;

    const size_t xt_bytes = (size_t)CIN * P * sizeof(float);   // 12.8 MB
    if (ws_size >= xt_bytes) {
        float* xT = (float*)d_ws;
        transpose_x<<<dim3(49, 256), 256, 0, stream>>>(x, xT);
        ndist_kernel<<<dim3(COUT / CPW, NPT), 64, 0, stream>>>(xT, w, bias, out);
    } else {
        ndist_fallback<<<dim3(COUT / 16, 49), 128, 0, stream>>>(x, w, bias, out);
    }
}